// Round 4
// baseline (25.865 us; speedup 1.0000x reference)
//
#include <hip/hip_runtime.h>
#include <cstdint>

// EmbeddingDropout: out[b,s,:] = mask[words[b,s]] * weight[words[b,s], :]
// mask[v] from jax.random.bernoulli(jax.random.key(42), 0.9, (VOCAB,1)),
// jax_threefry_partitionable=True scheme (CONFIRMED by round-2 pass):
//   (y0,y1) = threefry2x32(key=(0,42), ctr=(0,v));  bits = y0 ^ y1
//   u = bitcast((bits>>9)|0x3f800000) - 1.0f;  keep = u < 0.9f;  mask = keep/0.9
//
// Structure: 8 rows per 256-thread block -> grid 2048 = 8 blocks/CU x 4 waves
// = 32 waves/CU (full occupancy); 8 independent index->threefry->row chains
// per wave for latency hiding. Non-temporal stores (clang ext_vector_type --
// HIP float4 is rejected by the builtin) keep L2/L3 for reused weight rows.

#define DIM 1024
#define ROWS_PER_BLOCK 8

typedef float f32x4 __attribute__((ext_vector_type(4)));

__device__ __forceinline__ uint32_t rotl32(uint32_t x, int d) {
    return (x << d) | (x >> (32 - d));
}

// Threefry-2x32, 20 rounds, key (0, 42) baked in (jax.random.key(42)).
__device__ __forceinline__ void threefry2x32_k42(uint32_t& x0, uint32_t& x1) {
    const uint32_t ks0 = 0u;
    const uint32_t ks1 = 42u;
    const uint32_t ks2 = 0x1BD11BDAu ^ ks0 ^ ks1;
    x0 += ks0; x1 += ks1;
#define RND(r) { x0 += x1; x1 = rotl32(x1, (r)); x1 ^= x0; }
#define R4A RND(13) RND(15) RND(26) RND(6)
#define R4B RND(17) RND(29) RND(16) RND(24)
    R4A x0 += ks1; x1 += ks2 + 1u;
    R4B x0 += ks2; x1 += ks0 + 2u;
    R4A x0 += ks0; x1 += ks1 + 3u;
    R4B x0 += ks1; x1 += ks2 + 4u;
    R4A x0 += ks2; x1 += ks0 + 5u;
#undef R4A
#undef R4B
#undef RND
}

// Partitionable-mode mask for vocab row v: ctr = (0, v), bits = y0 ^ y1.
__device__ __forceinline__ float dropout_mask(uint32_t v) {
    uint32_t x0 = 0u;   // hi32 of the uint64 iota counter
    uint32_t x1 = v;    // lo32
    threefry2x32_k42(x0, x1);
    const uint32_t bits = x0 ^ x1;
    const float u = __uint_as_float((bits >> 9) | 0x3f800000u) - 1.0f;
    return (u < 0.9f) ? (1.0f / 0.9f) : 0.0f;
}

__global__ __launch_bounds__(256) void EmbeddingDropout_7318624272856_kernel(
        const int* __restrict__ words,
        const float* __restrict__ weight,
        float* __restrict__ out,
        int nrows) {
    const int t = threadIdx.x;
    const int base = blockIdx.x * ROWS_PER_BLOCK;

#pragma unroll
    for (int r = 0; r < ROWS_PER_BLOCK; ++r) {
        const int row = base + r;
        if (row >= nrows) break;
        const uint32_t v = (uint32_t)words[row];   // block-uniform -> s_load
        const float m = dropout_mask(v);           // scalarizes to SALU

        const f32x4 w =
            reinterpret_cast<const f32x4*>(weight + (size_t)v * DIM)[t];
        const f32x4 o = w * m;
        __builtin_nontemporal_store(
            o, reinterpret_cast<f32x4*>(out + (size_t)row * DIM) + t);
    }
}

extern "C" void kernel_launch(void* const* d_in, const int* in_sizes, int n_in,
                              void* d_out, int out_size, void* d_ws, size_t ws_size,
                              hipStream_t stream) {
    const int*   words  = (const int*)d_in[0];   // [BATCH*SEQ] int32
    const float* weight = (const float*)d_in[1]; // [VOCAB*DIM] fp32
    float*       out    = (float*)d_out;         // [BATCH*SEQ*DIM] fp32

    const int nrows = in_sizes[0];               // 16384
    const int grid = (nrows + ROWS_PER_BLOCK - 1) / ROWS_PER_BLOCK;  // 2048
    EmbeddingDropout_7318624272856_kernel<<<grid, 256, 0, stream>>>(
        words, weight, out, nrows);
}

// Round 5
// 25.226 us; speedup vs baseline: 1.0253x; 1.0253x over previous
//
#include <hip/hip_runtime.h>
#include <cstdint>

// EmbeddingDropout: out[b,s,:] = mask[words[b,s]] * weight[words[b,s], :]
// mask[v] from jax.random.bernoulli(jax.random.key(42), 0.9, (VOCAB,1)),
// jax_threefry_partitionable=True scheme (CONFIRMED by round-2 pass):
//   (y0,y1) = threefry2x32(key=(0,42), ctr=(0,v));  bits = y0 ^ y1
//   u = bitcast((bits>>9)|0x3f800000) - 1.0f;  keep = u < 0.9f;  mask = keep/0.9
//
// Structure: 8 rows per 256-thread block, grid 2048 = 8 blocks/CU x 4 waves =
// 32 waves/CU. Round-4 lesson: perf is insensitive to rows/block & occupancy
// (25.3 vs 25.9 us) -> mixed-stream BW-limited, not latency-limited.
// This round: dropped rows (~10%) skip the 4KB weight fetch entirely and
// store zeros (branch is uniform per row -> scalar branch, no divergence).

#define DIM 1024
#define ROWS_PER_BLOCK 8

typedef float f32x4 __attribute__((ext_vector_type(4)));

__device__ __forceinline__ uint32_t rotl32(uint32_t x, int d) {
    return (x << d) | (x >> (32 - d));
}

// Threefry-2x32, 20 rounds, key (0, 42) baked in (jax.random.key(42)).
__device__ __forceinline__ void threefry2x32_k42(uint32_t& x0, uint32_t& x1) {
    const uint32_t ks0 = 0u;
    const uint32_t ks1 = 42u;
    const uint32_t ks2 = 0x1BD11BDAu ^ ks0 ^ ks1;
    x0 += ks0; x1 += ks1;
#define RND(r) { x0 += x1; x1 = rotl32(x1, (r)); x1 ^= x0; }
#define R4A RND(13) RND(15) RND(26) RND(6)
#define R4B RND(17) RND(29) RND(16) RND(24)
    R4A x0 += ks1; x1 += ks2 + 1u;
    R4B x0 += ks2; x1 += ks0 + 2u;
    R4A x0 += ks0; x1 += ks1 + 3u;
    R4B x0 += ks1; x1 += ks2 + 4u;
    R4A x0 += ks2; x1 += ks0 + 5u;
#undef R4A
#undef R4B
#undef RND
}

// Partitionable-mode keep-test for vocab row v: ctr = (0, v), bits = y0 ^ y1.
__device__ __forceinline__ bool keep_row(uint32_t v) {
    uint32_t x0 = 0u;   // hi32 of the uint64 iota counter
    uint32_t x1 = v;    // lo32
    threefry2x32_k42(x0, x1);
    const uint32_t bits = x0 ^ x1;
    const float u = __uint_as_float((bits >> 9) | 0x3f800000u) - 1.0f;
    return u < 0.9f;
}

__global__ __launch_bounds__(256) void EmbeddingDropout_7318624272856_kernel(
        const int* __restrict__ words,
        const float* __restrict__ weight,
        float* __restrict__ out,
        int nrows) {
    const int t = threadIdx.x;
    const int base = blockIdx.x * ROWS_PER_BLOCK;

#pragma unroll
    for (int r = 0; r < ROWS_PER_BLOCK; ++r) {
        const int row = base + r;
        if (row >= nrows) break;
        const uint32_t v = (uint32_t)words[row];   // block-uniform -> s_load
        f32x4* const dst = reinterpret_cast<f32x4*>(out + (size_t)row * DIM) + t;

        if (keep_row(v)) {                         // uniform -> scalar branch
            const f32x4 w =
                reinterpret_cast<const f32x4*>(weight + (size_t)v * DIM)[t];
            __builtin_nontemporal_store(w * (1.0f / 0.9f), dst);
        } else {
            // dropped row: no weight fetch, output is exactly zero
            __builtin_nontemporal_store((f32x4)0.0f, dst);
        }
    }
}

extern "C" void kernel_launch(void* const* d_in, const int* in_sizes, int n_in,
                              void* d_out, int out_size, void* d_ws, size_t ws_size,
                              hipStream_t stream) {
    const int*   words  = (const int*)d_in[0];   // [BATCH*SEQ] int32
    const float* weight = (const float*)d_in[1]; // [VOCAB*DIM] fp32
    float*       out    = (float*)d_out;         // [BATCH*SEQ*DIM] fp32

    const int nrows = in_sizes[0];               // 16384
    const int grid = (nrows + ROWS_PER_BLOCK - 1) / ROWS_PER_BLOCK;  // 2048
    EmbeddingDropout_7318624272856_kernel<<<grid, 256, 0, stream>>>(
        words, weight, out, nrows);
}